// Round 1
// baseline (140.959 us; speedup 1.0000x reference)
//
#include <hip/hip_runtime.h>

// MinibatchDiscrimination: out = concat(x, feats) where
//   M = x @ T  -> [N, K, D],  N=16384, F=256, K=32, D=16
//   feats[n,k1] = sum_d exp(-sum_k2 |M[n,k2,d] - M[n,k1,d]|)
//
// Round 1: fused fp32 kernel (baseline). VALU-bound by design analysis:
// GEMM floor ~27us on fp32 vector ALU; memory floor ~6us. MFMA is round 2.

#define NF       256      // F
#define KD       512      // K*D
#define NK       32       // K
#define ND       16       // D
#define OUTF     288      // F + K
#define TM       16       // samples per block
#define THREADS  256
#define MSTRIDE  520      // padded LDS row stride for M (floats); 520%32=8 -> <=2-way conflicts (free)

__global__ __launch_bounds__(THREADS, 3)
void mbd_fused_kernel(const float* __restrict__ x,
                      const float* __restrict__ Tm,
                      float* __restrict__ out) {
    __shared__ float xs[TM * NF];          // 16 KB, x tile
    __shared__ float Ms[TM * MSTRIDE];     // 32.5 KB, M tile (padded)

    const int t  = threadIdx.x;
    const int s0 = blockIdx.x * TM;        // first sample of this block

    // ---- load x tile to LDS; simultaneously write x passthrough to out ----
    // out rows are 288 floats (72 float4), first 64 float4 are x.
    {
        const float4* xg4 = (const float4*)(x + (size_t)s0 * NF);
        float4* xs4  = (float4*)xs;
        float4* out4 = (float4*)out;
        #pragma unroll
        for (int i = 0; i < 4; ++i) {
            int q = t + i * THREADS;            // 0..1023 (16 samples * 64 float4)
            float4 v = xg4[q];
            xs4[q] = v;
            int ss = q >> 6;                     // sample within tile
            int c  = q & 63;                     // float4 column
            out4[(size_t)(s0 + ss) * (OUTF / 4) + c] = v;
        }
    }
    __syncthreads();

    // ---- phase 1: GEMM. thread t computes columns j0=2t, j1=2t+1 for all 16 samples ----
    float acc0[TM], acc1[TM];
    #pragma unroll
    for (int s = 0; s < TM; ++s) { acc0[s] = 0.f; acc1[s] = 0.f; }

    const float* Trow = Tm + 2 * t;
    for (int f4 = 0; f4 < NF / 4; ++f4) {
        float2 tv0 = *(const float2*)(Trow + (size_t)(4 * f4 + 0) * KD);
        float2 tv1 = *(const float2*)(Trow + (size_t)(4 * f4 + 1) * KD);
        float2 tv2 = *(const float2*)(Trow + (size_t)(4 * f4 + 2) * KD);
        float2 tv3 = *(const float2*)(Trow + (size_t)(4 * f4 + 3) * KD);
        #pragma unroll
        for (int s = 0; s < TM; ++s) {
            float4 xv = *(const float4*)&xs[s * NF + 4 * f4];  // wave-uniform addr -> LDS broadcast
            acc0[s] = fmaf(xv.x, tv0.x, acc0[s]);
            acc0[s] = fmaf(xv.y, tv1.x, acc0[s]);
            acc0[s] = fmaf(xv.z, tv2.x, acc0[s]);
            acc0[s] = fmaf(xv.w, tv3.x, acc0[s]);
            acc1[s] = fmaf(xv.x, tv0.y, acc1[s]);
            acc1[s] = fmaf(xv.y, tv1.y, acc1[s]);
            acc1[s] = fmaf(xv.z, tv2.y, acc1[s]);
            acc1[s] = fmaf(xv.w, tv3.y, acc1[s]);
        }
    }

    #pragma unroll
    for (int s = 0; s < TM; ++s) {
        *(float2*)&Ms[s * MSTRIDE + 2 * t] = make_float2(acc0[s], acc1[s]);
    }
    __syncthreads();

    // ---- phase 2: pairwise L1 + exp + reduce over d ----
    // thread -> (s = t>>4, d = t&15). Load the 32 kernel values for (s,d) into
    // registers ONCE (32 LDS reads/thread), all-pairs in registers.
    {
        const int s = t >> 4;
        const int d = t & 15;
        const float* Mrow = &Ms[s * MSTRIDE];

        float v[NK];
        #pragma unroll
        for (int k = 0; k < NK; ++k) v[k] = Mrow[k * ND + d];

        float a[NK];
        #pragma unroll
        for (int k = 0; k < NK; ++k) a[k] = 0.f;

        // symmetric pairs: 496 * (sub + 2 add) instead of 1024 * (sub + add)
        #pragma unroll
        for (int i = 0; i < NK; ++i) {
            #pragma unroll
            for (int j = i + 1; j < NK; ++j) {
                float df = fabsf(v[i] - v[j]);
                a[i] += df;
                a[j] += df;
            }
        }

        // e = exp(-a); butterfly-sum across the 16 d-lanes (contiguous 16-lane groups)
        #pragma unroll
        for (int k = 0; k < NK; ++k) {
            float e = __expf(-a[k]);
            e += __shfl_xor(e, 1, 16);
            e += __shfl_xor(e, 2, 16);
            e += __shfl_xor(e, 4, 16);
            e += __shfl_xor(e, 8, 16);
            a[k] = e;   // feats[s][k], replicated across the 16 lanes
        }

        // lane d==0 of each group writes all 32 feats (static register indices)
        if (d == 0) {
            float* orow = out + (size_t)(s0 + s) * OUTF + NF;
            #pragma unroll
            for (int k = 0; k < NK; ++k) orow[k] = a[k];
        }
    }
}

extern "C" void kernel_launch(void* const* d_in, const int* in_sizes, int n_in,
                              void* d_out, int out_size, void* d_ws, size_t ws_size,
                              hipStream_t stream) {
    const float* x  = (const float*)d_in[0];   // [32*512, 256]
    const float* Tm = (const float*)d_in[1];   // [256, 512]
    float* out = (float*)d_out;                // [32*512, 288]

    const int n_samples = 32 * 512;
    dim3 grid(n_samples / TM);                 // 1024 blocks
    dim3 block(THREADS);
    hipLaunchKernelGGL(mbd_fused_kernel, grid, block, 0, stream, x, Tm, out);
}

// Round 2
// 98.796 us; speedup vs baseline: 1.4268x; 1.4268x over previous
//
#include <hip/hip_runtime.h>

// MinibatchDiscrimination fused, round 2: bf16 MFMA GEMM.
//   M = x @ T  -> [N, K, D], N=16384, F=256, K=32, D=16
//   feats[n,k1] = sum_d exp(-sum_k2 |M[n,k2,d] - M[n,k1,d]|)
//   out = concat(x, feats)
//
// R1 post-mortem: fp32 GEMM was LDS-return-path bound (16384 ds_read_b128/CU
// x 12cyc = 82us == measured 84us). Fix: MFMA (~2us of matrix pipe), A-frags
// from LDS, B-frags pre-packed to d_ws by a tiny kernel so global_load_dwordx4
// at lane*16B is the fragment. feats numerics: exp(-~560) == 0 in fp32, so
// bf16 GEMM error (~0.5 abs in M) cannot change the output.

#define NF       256
#define KD       512
#define NK       32
#define ND       16
#define OUTF     288
#define TM       32            // samples per block
#define THREADS  256
#define XS_STR   264           // bf16 elems per xs row (256+8 pad: 2-way conflicts only)
#define MS_STR   36            // bf16 elems per Ms row [col][sample] (32+4 pad, keeps 8B align)

typedef __attribute__((ext_vector_type(8))) short short8v;   // 8 bf16 = 4 VGPR (MFMA A/B frag)
typedef __attribute__((ext_vector_type(4))) short short4v;   // 8 B
typedef __attribute__((ext_vector_type(4))) float f32x4;     // MFMA C/D frag

static __device__ inline unsigned short f2bf(float f) {
    unsigned int u = __float_as_uint(f);
    return (unsigned short)((u + 0x7FFFu + ((u >> 16) & 1u)) >> 16);  // RNE
}
static __device__ inline float bf2f(unsigned short h) {
    return __uint_as_float(((unsigned int)h) << 16);
}

// ---- pack T [256][512] fp32 -> bf16 B-fragments in ws ----
// Fragment tile (ntile,ks): 64 lanes x 8 bf16, elem j of lane L = B[ks*32+(L>>4)*8+j][ntile*16+(L&15)]
__global__ void tpack_kernel(const float* __restrict__ T, unsigned short* __restrict__ Tp) {
    int tid  = blockIdx.x * blockDim.x + threadIdx.x;   // 0..16383
    int lane = tid & 63;
    int tile = tid >> 6;                                // ntile*8 + ks, 0..255
    int ks   = tile & 7;
    int nt   = tile >> 3;
    int n  = nt * 16 + (lane & 15);
    int kb = ks * 32 + (lane >> 4) * 8;
    unsigned short v[8];
#pragma unroll
    for (int j = 0; j < 8; ++j) v[j] = f2bf(T[(size_t)(kb + j) * KD + n]);
    short4v* dst = (short4v*)&Tp[(size_t)tid * 8];
    dst[0] = *(short4v*)&v[0];
    dst[1] = *(short4v*)&v[4];
}

__global__ __launch_bounds__(THREADS, 2)
void mbd_mfma_kernel(const float* __restrict__ x,
                     const unsigned short* __restrict__ Tp,
                     float* __restrict__ out) {
    __shared__ unsigned short xs[TM * XS_STR];   // 16.5 KB  A tile, bf16
    __shared__ unsigned short Ms[KD * MS_STR];   // 36.9 KB  M transposed [col][sample], bf16

    const int t    = threadIdx.x;
    const int lane = t & 63;
    const int w    = t >> 6;            // wave 0..3
    const int s0   = blockIdx.x * TM;

    // ---- phase 0: load x tile, write passthrough, convert to bf16 LDS ----
    {
        const float4* xg4 = (const float4*)(x + (size_t)s0 * NF);
        float4* out4 = (float4*)out;
#pragma unroll
        for (int i = 0; i < 8; ++i) {
            int q   = t + i * THREADS;      // 0..2047 = 32 rows * 64 float4
            int row = q >> 6;
            int col = q & 63;
            float4 v = xg4[q];
            out4[(size_t)(s0 + row) * (OUTF / 4) + col] = v;
            unsigned short b[4] = { f2bf(v.x), f2bf(v.y), f2bf(v.z), f2bf(v.w) };
            *(short4v*)&xs[row * XS_STR + col * 4] = *(short4v*)b;
        }
    }
    __syncthreads();

    // ---- phase 1: MFMA GEMM. wave w -> cols [w*128, w*128+128), 2 m-tiles x 8 n-tiles ----
    const int mrow = lane & 15;
    const int quad = lane >> 4;

    f32x4 acc[2][8];
#pragma unroll
    for (int mt = 0; mt < 2; ++mt)
#pragma unroll
        for (int i = 0; i < 8; ++i) acc[mt][i] = (f32x4){0.f, 0.f, 0.f, 0.f};

    const short8v* TpF = (const short8v*)Tp;   // fragment tiles: 64 short8 each
#pragma unroll
    for (int ks = 0; ks < 8; ++ks) {
        short8v a0 = *(const short8v*)&xs[(mrow)      * XS_STR + ks * 32 + quad * 8];
        short8v a1 = *(const short8v*)&xs[(16 + mrow) * XS_STR + ks * 32 + quad * 8];
#pragma unroll
        for (int i = 0; i < 8; ++i) {
            int ntile = w * 8 + i;
            short8v b = TpF[(ntile * 8 + ks) * 64 + lane];
            acc[0][i] = __builtin_amdgcn_mfma_f32_16x16x32_bf16(a0, b, acc[0][i], 0, 0, 0);
            acc[1][i] = __builtin_amdgcn_mfma_f32_16x16x32_bf16(a1, b, acc[1][i], 0, 0, 0);
        }
    }

    // ---- epilogue: acc -> Ms[col][sample] bf16. C layout: col=lane&15, row=quad*4+reg ----
#pragma unroll
    for (int mt = 0; mt < 2; ++mt)
#pragma unroll
        for (int i = 0; i < 8; ++i) {
            int n    = (w * 8 + i) * 16 + mrow;
            int srow = mt * 16 + quad * 4;
            f32x4 c = acc[mt][i];
            unsigned short b[4] = { f2bf(c.x), f2bf(c.y), f2bf(c.z), f2bf(c.w) };
            *(short4v*)&Ms[n * MS_STR + srow] = *(short4v*)b;   // 8B-aligned ds_write_b64
        }
    __syncthreads();

    // ---- phase 2: pairwise L1 + exp + reduce over d ----
    const int d    = t & 15;
    const int sgrp = t >> 4;          // 0..15
#pragma unroll
    for (int p = 0; p < 2; ++p) {
        const int s = p * 16 + sgrp;

        float v[NK];
#pragma unroll
        for (int k = 0; k < NK; ++k) v[k] = bf2f(Ms[(k * ND + d) * MS_STR + s]);

        float a_[NK];
#pragma unroll
        for (int k = 0; k < NK; ++k) a_[k] = 0.f;
#pragma unroll
        for (int i = 0; i < NK; ++i)
#pragma unroll
            for (int j = i + 1; j < NK; ++j) {
                float df = fabsf(v[i] - v[j]);
                a_[i] += df;
                a_[j] += df;
            }

        float cur[NK];
#pragma unroll
        for (int k = 0; k < NK; ++k) cur[k] = __expf(-a_[k]);

        // recursive-halving sum over the 16 d-lanes; lane d ends with k=2d, 2d+1
#define STAGE(MASK, HALF) do {                                   \
            const bool up = (d & (MASK)) != 0;                   \
            _Pragma("unroll")                                    \
            for (int j = 0; j < (HALF); ++j) {                   \
                float send = up ? cur[j] : cur[(HALF) + j];      \
                float keep = up ? cur[(HALF) + j] : cur[j];      \
                float recv = __shfl_xor(send, (MASK), 16);       \
                cur[j] = keep + recv;                            \
            }                                                    \
        } while (0)
        STAGE(8, 16); STAGE(4, 8); STAGE(2, 4); STAGE(1, 2);
#undef STAGE

        float2 res = make_float2(cur[0], cur[1]);
        *(float2*)(out + (size_t)(s0 + s) * OUTF + NF + 2 * d) = res;
    }
}

extern "C" void kernel_launch(void* const* d_in, const int* in_sizes, int n_in,
                              void* d_out, int out_size, void* d_ws, size_t ws_size,
                              hipStream_t stream) {
    const float* x  = (const float*)d_in[0];   // [16384, 256]
    const float* Tm = (const float*)d_in[1];   // [256, 512]
    float* out = (float*)d_out;                // [16384, 288]
    unsigned short* Tp = (unsigned short*)d_ws; // 256 KB bf16 fragment pack

    hipLaunchKernelGGL(tpack_kernel, dim3(64), dim3(256), 0, stream, Tm, Tp);
    hipLaunchKernelGGL(mbd_mfma_kernel, dim3(16384 / TM), dim3(THREADS), 0, stream, x, Tp, out);
}